// Round 6
// baseline (161.512 us; speedup 1.0000x reference)
//
#include <hip/hip_runtime.h>

#define NEGV -10000.0f

typedef _Float16 f16x8 __attribute__((ext_vector_type(8)));
typedef _Float16 f16x4 __attribute__((ext_vector_type(4)));
typedef _Float16 f16x2 __attribute__((ext_vector_type(2)));
typedef float floatx4 __attribute__((ext_vector_type(4)));

// key (0..319) -> source sequence row. keys 0..63 local to query block nblk,
// keys 64..319 are the 256 global positions {0,61,62,63}+64j.
__device__ __forceinline__ int src_row(int key, int nblk) {
    if (key < 64) return nblk * 64 + key;
    int g = key - 64;
    int p = g & 3;
    return (g >> 2) * 64 + (p ? (60 + p) : 0);
}

__global__ __launch_bounds__(256, 4)
void sparse_attn_kernel(const float* __restrict__ Q, const float* __restrict__ K,
                        const float* __restrict__ V, const float* __restrict__ M,
                        float* __restrict__ O)
{
    // XCD swizzle: 4 whole heads per XCD so the head's global K/V rows stay in L2.
    const int x    = blockIdx.x;
    const int bh   = (x & 7) * 4 + ((x >> 3) >> 6);   // 0..31
    const int nblk = (x >> 3) & 63;                   // query block in head
    const int b    = bh >> 4;

    const size_t hoff = (size_t)bh * (4096 * 64);
    const float* Qh = Q + hoff;
    const float* Kh = K + hoff;
    const float* Vh = V + hoff;
    float*       Oh = O + hoff;
    const float* Mb = M + (size_t)b * 4096;

    // 40960 B -> 4 blocks/CU.
    // Phase 1 (QK): K image = 40 slabs x 1024 B, slab s lane l at elem s*512+l*8.
    // Phase 2 (PV), aliasing the dead K image:
    //   [0,4096)      P ping-pong: wave wv, buf pp at wv*1024 + pp*512 (f16 elems)
    //   [4096,4736)   MaskAdd: 320 floats
    //   [4736,14976)  VT half image: 160 keys x 64 d fragment slabs (swizzled)
    __shared__ _Float16 smem[20480];
    float*    MaskLDS = (float*)(smem + 4096);
    _Float16* VTbase  = smem + 4736;

    const int tid  = threadIdx.x;
    const int lane = tid & 63;
    const int wv   = tid >> 6;          // wave -> query rows wv*16..+15
    const int m    = lane & 15;
    const int quad = lane >> 4;
    const int sgl  = lane ^ (lane >> 2);               // swizzled VT read group
    const int cg   = lane & 15;                        // V col granule (4 floats)
    const int ppb  = ((wv << 2) + (lane >> 4) + ((cg >> 2) << 2)) & 15;

    // ---- mask raw loads (converted + staged to LDS after B2) ----
    float mraw0 = Mb[src_row(tid, nblk)];
    float mraw1 = (tid < 64) ? Mb[src_row(256 + tid, nblk)] : 1.0f;

    // ---- Q fragments direct from global (fp16); B-operand layout ----
    const int qrow = nblk * 64 + wv * 16 + m;
    f16x8 qf[2];
    #pragma unroll
    for (int c = 0; c < 2; ++c) {
        const float* src = Qh + (size_t)qrow * 64 + c * 32 + quad * 8;
        float4 f0 = *(const float4*)src;
        float4 f1 = *(const float4*)(src + 4);
        qf[c][0] = (_Float16)f0.x; qf[c][1] = (_Float16)f0.y;
        qf[c][2] = (_Float16)f0.z; qf[c][3] = (_Float16)f0.w;
        qf[c][4] = (_Float16)f1.x; qf[c][5] = (_Float16)f1.y;
        qf[c][6] = (_Float16)f1.z; qf[c][7] = (_Float16)f1.w;
    }

    // ---- stage K in fragment layout (wave-linear b128 writes) ----
    #pragma unroll
    for (int it = 0; it < 10; ++it) {
        int S    = it * 256 + tid;                       // 16B slot id, 0..2559
        int row  = ((S >> 7) * 16) + (S & 15);           // t*16 + n (key)
        int col0 = ((S >> 6) & 1) * 32 + ((S & 63) >> 4) * 8;
        const float* src = Kh + (size_t)src_row(row, nblk) * 64 + col0;
        float4 f0 = *(const float4*)src;
        float4 f1 = *(const float4*)(src + 4);
        f16x8 o;
        o[0] = (_Float16)f0.x; o[1] = (_Float16)f0.y;
        o[2] = (_Float16)f0.z; o[3] = (_Float16)f0.w;
        o[4] = (_Float16)f1.x; o[5] = (_Float16)f1.y;
        o[6] = (_Float16)f1.z; o[7] = (_Float16)f1.w;
        *(f16x8*)(&smem[S * 8]) = o;
    }

    __syncthreads();   // B1: K image complete

    // ---- QK^T transposed: S^T = K·Q^T. A=K frag, B=Q frag.
    //      C/D: col = lane&15 = query m, row = quad*4+r = key within tile. ----
    floatx4 acc[20] = {};
    #pragma unroll
    for (int t = 0; t < 20; ++t) {
        #pragma unroll
        for (int c = 0; c < 2; ++c) {
            f16x8 kf = *(const f16x8*)(&smem[(t * 2 + c) * 512 + lane * 8]);
            acc[t] = __builtin_amdgcn_mfma_f32_16x16x32_f16(kf, qf[c], acc[t], 0, 0, 0);
        }
    }

    __syncthreads();   // B2: K image dead; PV-phase regions live

    // ---- stage mask adds ----
    MaskLDS[tid] = (mraw0 == 0.0f) ? NEGV : 0.0f;
    if (tid < 64) MaskLDS[256 + tid] = (mraw1 == 0.0f) ? NEGV : 0.0f;

    // ---- stage VT half 0 (keys 0..159): load -> cvt -> swizzled frag image ----
    #pragma unroll
    for (int s = 0; s < 5; ++s) {
        int rl = 2 * (s * 16 + ppb);                     // chunk-local even row
        float4 f0 = *(const float4*)(Vh + (size_t)src_row(rl,     nblk) * 64 + cg * 4);
        float4 f1 = *(const float4*)(Vh + (size_t)src_row(rl + 1, nblk) * 64 + cg * 4);
        int slab = (cg >> 2) * 5 + (rl >> 5);
        int gq   = ((rl & 31) >> 3) * 16;
        int j0   = rl & 7;
        f16x2 pk[4];
        pk[0][0] = (_Float16)f0.x; pk[0][1] = (_Float16)f1.x;
        pk[1][0] = (_Float16)f0.y; pk[1][1] = (_Float16)f1.y;
        pk[2][0] = (_Float16)f0.z; pk[2][1] = (_Float16)f1.z;
        pk[3][0] = (_Float16)f0.w; pk[3][1] = (_Float16)f1.w;
        #pragma unroll
        for (int e = 0; e < 4; ++e) {
            int g  = gq + (cg & 3) * 4 + e;
            int sg = g ^ (g >> 2);
            *(f16x2*)(&VTbase[slab * 512 + sg * 8 + j0]) = pk[e];
        }
    }

    __syncthreads();   // B3: mask + VT0 ready

    // ---- mask add + softmax. Lane owns query m; keys t*16+quad*4+r (80/lane).
    float mx = -3e38f;
    #pragma unroll
    for (int t = 0; t < 20; ++t) {
        floatx4 ma4 = *(const floatx4*)(&MaskLDS[t * 16 + quad * 4]);
        #pragma unroll
        for (int r = 0; r < 4; ++r) {
            acc[t][r] += ma4[r];
            mx = fmaxf(mx, acc[t][r]);
        }
    }
    mx = fmaxf(mx, __shfl_xor(mx, 16, 64));
    mx = fmaxf(mx, __shfl_xor(mx, 32, 64));
    float sum = 0.f;
    #pragma unroll
    for (int t = 0; t < 20; ++t)
        #pragma unroll
        for (int r = 0; r < 4; ++r) {
            float e = __expf(acc[t][r] - mx);
            acc[t][r] = e;
            sum += e;
        }
    sum += __shfl_xor(sum, 16, 64);
    sum += __shfl_xor(sum, 32, 64);
    const float rinv = 1.0f / sum;

    // ---- PV half 0: 5 chunks of 32 keys; P via wave-private ping-pong ----
    floatx4 oacc[4] = {};
    #pragma unroll
    for (int c = 0; c < 5; ++c) {
        _Float16* pb = smem + wv * 1024 + (c & 1) * 512;
        #pragma unroll
        for (int tp = 0; tp < 2; ++tp) {
            int T = c * 2 + tp;
            int g = (tp * 2 + (quad >> 1)) * 16 + m;
            f16x4 p4;
            #pragma unroll
            for (int r = 0; r < 4; ++r) p4[r] = (_Float16)(acc[T][r] * rinv);
            *(f16x4*)(&pb[g * 8 + (quad & 1) * 4]) = p4;
        }
        f16x8 pf = *(const f16x8*)(&pb[lane * 8]);       // in-wave lgkm ordering
        #pragma unroll
        for (int t = 0; t < 4; ++t) {
            f16x8 vf = *(const f16x8*)(&VTbase[(t * 5 + c) * 512 + sgl * 8]);
            oacc[t] = __builtin_amdgcn_mfma_f32_16x16x32_f16(pf, vf, oacc[t], 0, 0, 0);
        }
    }

    __syncthreads();   // B4: VT0 reads done

    // ---- stage VT half 1 (keys 160..319) ----
    #pragma unroll
    for (int s = 0; s < 5; ++s) {
        int rl  = 2 * (s * 16 + ppb);
        int key = 160 + rl;
        float4 f0 = *(const float4*)(Vh + (size_t)src_row(key,     nblk) * 64 + cg * 4);
        float4 f1 = *(const float4*)(Vh + (size_t)src_row(key + 1, nblk) * 64 + cg * 4);
        int slab = (cg >> 2) * 5 + (rl >> 5);
        int gq   = ((rl & 31) >> 3) * 16;
        int j0   = rl & 7;
        f16x2 pk[4];
        pk[0][0] = (_Float16)f0.x; pk[0][1] = (_Float16)f1.x;
        pk[1][0] = (_Float16)f0.y; pk[1][1] = (_Float16)f1.y;
        pk[2][0] = (_Float16)f0.z; pk[2][1] = (_Float16)f1.z;
        pk[3][0] = (_Float16)f0.w; pk[3][1] = (_Float16)f1.w;
        #pragma unroll
        for (int e = 0; e < 4; ++e) {
            int g  = gq + (cg & 3) * 4 + e;
            int sg = g ^ (g >> 2);
            *(f16x2*)(&VTbase[slab * 512 + sg * 8 + j0]) = pk[e];
        }
    }

    __syncthreads();   // B5: VT1 ready

    // ---- PV half 1 ----
    #pragma unroll
    for (int c = 0; c < 5; ++c) {
        _Float16* pb = smem + wv * 1024 + (c & 1) * 512;
        #pragma unroll
        for (int tp = 0; tp < 2; ++tp) {
            int T = 10 + c * 2 + tp;
            int g = (tp * 2 + (quad >> 1)) * 16 + m;
            f16x4 p4;
            #pragma unroll
            for (int r = 0; r < 4; ++r) p4[r] = (_Float16)(acc[T][r] * rinv);
            *(f16x4*)(&pb[g * 8 + (quad & 1) * 4]) = p4;
        }
        f16x8 pf = *(const f16x8*)(&pb[lane * 8]);
        #pragma unroll
        for (int t = 0; t < 4; ++t) {
            f16x8 vf = *(const f16x8*)(&VTbase[(t * 5 + c) * 512 + sgl * 8]);
            oacc[t] = __builtin_amdgcn_mfma_f32_16x16x32_f16(pf, vf, oacc[t], 0, 0, 0);
        }
    }

    // ---- epilogue: O rows = queries quad*4+r, cols = d t*16+m (already normalized) ----
    #pragma unroll
    for (int t = 0; t < 4; ++t)
        #pragma unroll
        for (int r = 0; r < 4; ++r)
            Oh[(size_t)(nblk * 64 + wv * 16 + quad * 4 + r) * 64 + t * 16 + m] = oacc[t][r];
}

extern "C" void kernel_launch(void* const* d_in, const int* in_sizes, int n_in,
                              void* d_out, int out_size, void* d_ws, size_t ws_size,
                              hipStream_t stream) {
    const float* q    = (const float*)d_in[0];
    const float* k    = (const float*)d_in[1];
    const float* v    = (const float*)d_in[2];
    const float* mask = (const float*)d_in[3];
    float* out = (float*)d_out;
    (void)in_sizes; (void)n_in; (void)out_size; (void)d_ws; (void)ws_size;
    sparse_attn_kernel<<<2 * 16 * 64, 256, 0, stream>>>(q, k, v, mask, out);
}